// Round 5
// baseline (432.166 us; speedup 1.0000x reference)
//
#include <hip/hip_runtime.h>
#include <hip/hip_bf16.h>
#include <stdint.h>

#define NTOT 65536   // B * N_NODE
#define NNODE 2048
#define CIN 12

__device__ __forceinline__ float bf2f(uint32_t u) {
    union { uint32_t i; float f; } v; v.i = u << 16; return v.f;
}
__device__ __forceinline__ uint16_t f2bf(float f) {
    union { float f; uint32_t i; } v; v.f = f;
    uint32_t x = v.i;
    uint32_t r = x + 0x7fffu + ((x >> 16) & 1u);
    return (uint16_t)(r >> 16);
}
__device__ __forceinline__ float bflo(uint32_t u) { return bf2f(u & 0xffffu); }
__device__ __forceinline__ float bfhi(uint32_t u) { return bf2f(u >> 16); }
__device__ __forceinline__ float sigmf(float x) { return 1.0f / (1.0f + __expf(-x)); }
__device__ __forceinline__ float lrelu(float v) { return v > 0.f ? v : 0.2f * v; }

// ---------------- dtype / layout detection (one wave) ----------------
__global__ void k_detect(const uint16_t* __restrict__ x16, const int* __restrict__ e32,
                         int* __restrict__ flags) {
    int lane = threadIdx.x;
    uint32_t u = x16[2 * lane];
    uint32_t ex = (u >> 7) & 0xFF;
    bool sane = (ex >= 0x60 && ex <= 0x9F) || (u == 0);
    unsigned long long bs = __ballot(sane);
    bool hi_zero = (e32[2 * lane + 1] == 0);
    unsigned long long bz = __ballot(hi_zero);
    if (lane == 0) {
        flags[0] = (__popcll(bs) >= 52) ? 1 : 0;
        flags[1] = (__popcll(bz) == 64) ? 2 : 1;
    }
}

// ---------------- small-tensor conversion to fp32 ----------------
__device__ __forceinline__ void cvt(const void* s, float* d, int i, int bf) {
    d[i] = bf ? bf2f(((const uint16_t*)s)[i]) : ((const float*)s)[i];
}

#define O_WG   16
#define O_AS   1168
#define O_AD   1264
#define O_BIAS 1360
#define O_BIH1 1376
#define O_BHH1 1504
#define O_BIH2 1632
#define O_BHH2 2144
#define O_BLIN 2656
#define O_END  21088

__global__ void __launch_bounds__(256) k_conv(
    const void* wg, const void* as_, const void* ad_, const void* bs,
    const void* b1, const void* bb1, const void* b2, const void* bb2,
    const void* bl, float* __restrict__ ws, const int* __restrict__ flags) {
    int bf = flags[0];
    int i = blockIdx.x * 256 + threadIdx.x;
    if (i < 1152)  { cvt(wg,  ws + O_WG,   i, bf); return; } i -= 1152;
    if (i < 96)    { cvt(as_, ws + O_AS,   i, bf); return; } i -= 96;
    if (i < 96)    { cvt(ad_, ws + O_AD,   i, bf); return; } i -= 96;
    if (i < 12)    { cvt(bs,  ws + O_BIAS, i, bf); return; } i -= 12;
    if (i < 128)   { cvt(b1,  ws + O_BIH1, i, bf); return; } i -= 128;
    if (i < 128)   { cvt(bb1, ws + O_BHH1, i, bf); return; } i -= 128;
    if (i < 512)   { cvt(b2,  ws + O_BIH2, i, bf); return; } i -= 512;
    if (i < 512)   { cvt(bb2, ws + O_BHH2, i, bf); return; } i -= 512;
    if (i < 18432) { cvt(bl,  ws + O_BLIN, i, bf); }
}

__global__ void k_zero(int* __restrict__ p) {
    p[blockIdx.x * 256 + threadIdx.x] = 0;
}

// ---------- fused node transform + attention scores ----------
__global__ void __launch_bounds__(256) k_nfa(const void* __restrict__ xraw,
                                             const float* __restrict__ Wg,
                                             const float* __restrict__ att,
                                             const int* __restrict__ flags,
                                             uint16_t* __restrict__ hfb,
                                             float* __restrict__ a_s, float* __restrict__ a_d) {
    __shared__ float sx[384];
    __shared__ float sw[1152];
    __shared__ float satt[192];
    __shared__ float sh[3072];
    int tid = threadIdx.x;
    int n0 = blockIdx.x * 32;
    if (flags[0]) {
        const uint32_t* xp = (const uint32_t*)xraw;
        for (int i = tid; i < 192; i += 256) {
            uint32_t u = xp[n0 * 6 + i];
            sx[2 * i] = bflo(u); sx[2 * i + 1] = bfhi(u);
        }
    } else {
        const float* xp = (const float*)xraw;
        for (int i = tid; i < 384; i += 256) sx[i] = xp[n0 * 12 + i];
    }
    for (int i = tid; i < 1152; i += 256) sw[i] = Wg[i];
    if (tid < 192) satt[tid] = att[tid];
    __syncthreads();
#pragma unroll
    for (int r = 0; r < 12; r++) {
        int idx = r * 256 + tid;
        int n = idx / 96, o = idx % 96;
        float acc = 0.f;
#pragma unroll
        for (int k = 0; k < 12; k++) acc += sx[n * 12 + k] * sw[k * 96 + o];
        sh[idx] = acc;
        hfb[n0 * 96 + idx] = f2bf(acc);
    }
    __syncthreads();
    {
        int nl = tid >> 3, h = tid & 7;
        const float* hr = sh + nl * 96 + h * 12;
        float s = 0.f, dd = 0.f;
#pragma unroll
        for (int c = 0; c < 12; c++) {
            float v = hr[c];
            s += v * satt[h * 12 + c];
            dd += v * satt[96 + h * 12 + c];
        }
        a_s[n0 * 8 + tid] = s;
        a_d[n0 * 8 + tid] = dd;
    }
}

// ---------- CSR build ----------
__global__ void k_hist(const int* __restrict__ e, int E, const int* __restrict__ flags,
                       int* __restrict__ deg, int* __restrict__ rank) {
    int i = blockIdx.x * 256 + threadIdx.x;
    if (i < E) {
        long st = flags[1];
        int d = e[st * (E + i)];
        rank[i] = atomicAdd(&deg[d], 1);
    }
}

__global__ void k_scanA(const int* __restrict__ deg, int* __restrict__ offsL,
                        int* __restrict__ bsum) {
    __shared__ int s[256];
    int t = threadIdx.x, i = blockIdx.x * 256 + t;
    int v = deg[i];
    s[t] = v; __syncthreads();
    for (int off = 1; off < 256; off <<= 1) {
        int a = (t >= off) ? s[t - off] : 0;
        __syncthreads();
        s[t] += a;
        __syncthreads();
    }
    offsL[i] = s[t] - v;
    if (t == 255) bsum[blockIdx.x] = s[255];
}

__global__ void k_scanB(const int* __restrict__ bsum, int* __restrict__ boff) {
    __shared__ int s[256];
    int t = threadIdx.x;
    int v = bsum[t];
    s[t] = v; __syncthreads();
    for (int off = 1; off < 256; off <<= 1) {
        int a = (t >= off) ? s[t - off] : 0;
        __syncthreads();
        s[t] += a;
        __syncthreads();
    }
    boff[t] = s[t] - v;
}

__global__ void k_scatter(const int* __restrict__ e, int E, const int* __restrict__ flags,
                          const int* __restrict__ offsL, const int* __restrict__ boff,
                          const int* __restrict__ rank, int* __restrict__ ssrc) {
    int i = blockIdx.x * 256 + threadIdx.x;
    if (i < E) {
        long st = flags[1];
        int s = e[st * i];
        int d = e[st * (E + i)];
        ssrc[offsL[d] + boff[d >> 8] + rank[i]] = s;
    }
}

// ---------- GAT aggregation: lane = (edge-slot, head), 8 edges/iter ----------
__global__ void __launch_bounds__(256) k_agg(
    const uint16_t* __restrict__ hfb, const float* __restrict__ a_s, const float* __restrict__ a_d,
    const int* __restrict__ offsL, const int* __restrict__ boff, const int* __restrict__ deg,
    const int* __restrict__ ssrc, const float* __restrict__ bias, float* __restrict__ gT) {
    __shared__ float sres[4][12];
    int tid = threadIdx.x, wave = tid >> 6, lane = tid & 63;
    int node = blockIdx.x * 4 + wave;
    int beg = offsL[node] + boff[node >> 8];
    int d = deg[node];
    int sub = lane >> 3, h = lane & 7;
    float adh = a_d[node * 8 + h];
    float acc[12];
    float wsum = 0.f;
#pragma unroll
    for (int c = 0; c < 12; c++) acc[c] = 0.f;
    if (sub == 0) {
        float w = __expf(lrelu(a_s[node * 8 + h] + adh));
        wsum = w;
        const uint2* hp = (const uint2*)(hfb + node * 96 + h * 12);
#pragma unroll
        for (int p = 0; p < 3; p++) {
            uint2 u = hp[p];
            acc[4 * p]     = w * bflo(u.x); acc[4 * p + 1] = w * bfhi(u.x);
            acc[4 * p + 2] = w * bflo(u.y); acc[4 * p + 3] = w * bfhi(u.y);
        }
    }
    for (int base = 0; base < d; base += 8) {
        int k = base + sub;
        if (k < d) {
            int s = ssrc[beg + k];
            float w = __expf(lrelu(a_s[s * 8 + h] + adh));
            wsum += w;
            const uint2* hp = (const uint2*)(hfb + s * 96 + h * 12);
#pragma unroll
            for (int p = 0; p < 3; p++) {
                uint2 u = hp[p];
                acc[4 * p]     += w * bflo(u.x); acc[4 * p + 1] += w * bfhi(u.x);
                acc[4 * p + 2] += w * bflo(u.y); acc[4 * p + 3] += w * bfhi(u.y);
            }
        }
    }
#pragma unroll
    for (int off = 8; off <= 32; off <<= 1) {
        wsum += __shfl_xor(wsum, off, 64);
#pragma unroll
        for (int c = 0; c < 12; c++) acc[c] += __shfl_xor(acc[c], off, 64);
    }
    float inv = 1.f / wsum;
#pragma unroll
    for (int c = 0; c < 12; c++) acc[c] *= inv;
#pragma unroll
    for (int off = 1; off <= 4; off <<= 1) {
#pragma unroll
        for (int c = 0; c < 12; c++) acc[c] += __shfl_xor(acc[c], off, 64);
    }
    if (lane == 0) {
#pragma unroll
        for (int c = 0; c < 12; c++) sres[wave][c] = acc[c];
    }
    __syncthreads();
    if (tid < 48) {
        int no = tid / 12, c = tid % 12;
        gT[c * NTOT + blockIdx.x * 4 + no] = sres[no][c] * 0.125f + bias[c];
    }
}

// ---------- Z1 = seq @ Wih1^T + biases (dual-path W) ----------
__global__ void __launch_bounds__(256) k_z1(const float* __restrict__ gT,
                                            const void* __restrict__ Wraw,
                                            const float* __restrict__ b1,
                                            const float* __restrict__ b2,
                                            const int* __restrict__ flags,
                                            float* __restrict__ Z1) {
    int t = blockIdx.x >> 5, b = blockIdx.x & 31;
    __shared__ float sv[2048];
    __shared__ float zp[256];
    for (int v = threadIdx.x; v < 2048; v += 256) sv[v] = gT[t * NTOT + b * NNODE + v];
    __syncthreads();
    int row = threadIdx.x & 127, half = threadIdx.x >> 7;
    const float4* sp = (const float4*)(sv + half * 1024);
    float acc = 0.f;
    if (flags[0]) {
        const uint4* wp = (const uint4*)((const uint16_t*)Wraw + row * 2048 + half * 1024);
        for (int k = 0; k < 128; k++) {
            uint4 u = wp[k];
            float4 A = sp[2 * k], B = sp[2 * k + 1];
            acc += bflo(u.x) * A.x + bfhi(u.x) * A.y + bflo(u.y) * A.z + bfhi(u.y) * A.w
                 + bflo(u.z) * B.x + bfhi(u.z) * B.y + bflo(u.w) * B.z + bfhi(u.w) * B.w;
        }
    } else {
        const float4* wp = (const float4*)((const float*)Wraw + row * 2048 + half * 1024);
        for (int k = 0; k < 256; k++) {
            float4 w = wp[k], s = sp[k];
            acc += w.x * s.x + w.y * s.y + w.z * s.z + w.w * s.w;
        }
    }
    zp[threadIdx.x] = acc;
    __syncthreads();
    if (threadIdx.x < 128)
        Z1[t * 4096 + b * 128 + threadIdx.x] =
            zp[threadIdx.x] + zp[threadIdx.x + 128] + b1[threadIdx.x] + b2[threadIdx.x];
}

// ---------- fused LSTM1 + Z2 projection + LSTM2 (one block per batch) ----------
// Register-resident weights; h-broadcast via shuffles (no LDS in inner loops).
__global__ void __launch_bounds__(512) k_rec(const float* __restrict__ Z1,
                                             const void* __restrict__ Whh1r,
                                             const void* __restrict__ Wih2r,
                                             const void* __restrict__ Whh2r,
                                             const float* __restrict__ b2i,
                                             const float* __restrict__ b2h,
                                             const int* __restrict__ flags,
                                             float* __restrict__ h2l) {
    int b = blockIdx.x, row = threadIdx.x, lane = threadIdx.x & 63;
    __shared__ float h1s[32];
    __shared__ float zb1[128];
    __shared__ float hb2[128];
    __shared__ float zb2[512];
    int bf = flags[0];

    uint32_t w2r[64];   // Whh2 row (bf16 pairs)
    uint32_t wi2[16];   // Wih2 row
    uint32_t w1r[16];   // Whh1 row (rows<128)
    if (bf) {
        const uint32_t* p = (const uint32_t*)Whh2r + row * 64;
#pragma unroll
        for (int j = 0; j < 64; j++) w2r[j] = p[j];
        const uint32_t* q = (const uint32_t*)Wih2r + row * 16;
#pragma unroll
        for (int j = 0; j < 16; j++) wi2[j] = q[j];
        if (row < 128) {
            const uint32_t* r1 = (const uint32_t*)Whh1r + row * 16;
#pragma unroll
            for (int j = 0; j < 16; j++) w1r[j] = r1[j];
        }
    }
    float zbias = b2i[row] + b2h[row];
    if (row < 32) h1s[row] = 0.f;
    if (row < 128) hb2[row] = 0.f;
    float c1 = 0.f, c2 = 0.f;
    __syncthreads();

    for (int t = 0; t < 12; t++) {
        // recurrent part of LSTM2 gate pre-activation: uses h2(t-1)
        float2 hp = *(const float2*)&hb2[2 * lane];
        float zrec = 0.f;
        if (bf) {
#pragma unroll
            for (int j = 0; j < 64; j++) {
                float a = __shfl(hp.x, j, 64);
                float bb = __shfl(hp.y, j, 64);
                uint32_t u = w2r[j];
                zrec += bflo(u) * a + bfhi(u) * bb;
            }
        } else {
            const float* wf = (const float*)Whh2r + row * 128;
            for (int j = 0; j < 128; j++) zrec += wf[j] * hb2[j];
        }
        // LSTM1 matvec (rows<128 == waves 0,1)
        if (row < 128) {
            float z = Z1[t * 4096 + b * 128 + row];
            if (bf) {
                float2 q1 = *(const float2*)&h1s[2 * (lane & 15)];
#pragma unroll
                for (int j = 0; j < 16; j++) {
                    float a = __shfl(q1.x, j, 64);
                    float bb = __shfl(q1.y, j, 64);
                    uint32_t u = w1r[j];
                    z += bflo(u) * a + bfhi(u) * bb;
                }
            } else {
                const float* wf = (const float*)Whh1r + row * 32;
                for (int j = 0; j < 32; j++) z += wf[j] * h1s[j];
            }
            zb1[row] = z;
        }
        __syncthreads();   // B1: zb1 ready, everyone done reading hb2/h1s
        if (row < 32) {
            float iv = zb1[row], fv = zb1[32 + row], gv = zb1[64 + row], ov = zb1[96 + row];
            c1 = sigmf(fv) * c1 + sigmf(iv) * tanhf(gv);
            h1s[row] = sigmf(ov) * tanhf(c1);
        }
        __syncthreads();   // B2: h1s(t) ready
        {
            float z = zrec + zbias;
            if (bf) {
                float2 q2 = *(const float2*)&h1s[2 * (lane & 15)];
#pragma unroll
                for (int j = 0; j < 16; j++) {
                    float a = __shfl(q2.x, j, 64);
                    float bb = __shfl(q2.y, j, 64);
                    uint32_t u = wi2[j];
                    z += bflo(u) * a + bfhi(u) * bb;
                }
            } else {
                const float* wf = (const float*)Wih2r + row * 32;
                for (int j = 0; j < 32; j++) z += wf[j] * h1s[j];
            }
            zb2[row] = z;
        }
        __syncthreads();   // B3: zb2 ready
        if (row < 128) {
            float iv = zb2[row], fv = zb2[128 + row], gv = zb2[256 + row], ov = zb2[384 + row];
            c2 = sigmf(fv) * c2 + sigmf(iv) * tanhf(gv);
            float h = sigmf(ov) * tanhf(c2);
            hb2[row] = h;
            if (t == 11) h2l[b * 128 + row] = h;
        }
        __syncthreads();   // B4: hb2(t) ready
    }
}

// ---------- final linear (dual-path W) ----------
__global__ void __launch_bounds__(256) k_lin(const float* __restrict__ h2l,
                                             const void* __restrict__ Wraw,
                                             const float* __restrict__ bl,
                                             const int* __restrict__ flags,
                                             void* __restrict__ outv) {
    __shared__ float hl[8 * 128];
    int bg = blockIdx.y;
    for (int i = threadIdx.x; i < 1024; i += 256) hl[i] = h2l[bg * 1024 + i];
    __syncthreads();
    int o = blockIdx.x * 256 + threadIdx.x;
    float bb = bl[o];
    float acc[8];
#pragma unroll
    for (int b = 0; b < 8; b++) acc[b] = bb;
    int bf = flags[0];
    if (bf) {
        const uint4* wp = (const uint4*)((const uint16_t*)Wraw + o * 128);
        for (int k = 0; k < 16; k++) {
            uint4 u = wp[k];
            float w0 = bflo(u.x), w1 = bfhi(u.x), w2 = bflo(u.y), w3 = bfhi(u.y);
            float w4 = bflo(u.z), w5 = bfhi(u.z), w6 = bflo(u.w), w7 = bfhi(u.w);
#pragma unroll
            for (int b = 0; b < 8; b++) {
                const float* h8 = hl + b * 128 + k * 8;
                acc[b] += w0 * h8[0] + w1 * h8[1] + w2 * h8[2] + w3 * h8[3]
                        + w4 * h8[4] + w5 * h8[5] + w6 * h8[6] + w7 * h8[7];
            }
        }
    } else {
        const float4* wp = (const float4*)((const float*)Wraw + o * 128);
        for (int k = 0; k < 32; k++) {
            float4 w = wp[k];
#pragma unroll
            for (int b = 0; b < 8; b++) {
                const float* h4 = hl + b * 128 + k * 4;
                acc[b] += w.x * h4[0] + w.y * h4[1] + w.z * h4[2] + w.w * h4[3];
            }
        }
    }
    if (bf) {
        uint16_t* out = (uint16_t*)outv;
#pragma unroll
        for (int b = 0; b < 8; b++) out[(bg * 8 + b) * 18432 + o] = f2bf(acc[b]);
    } else {
        float* out = (float*)outv;
#pragma unroll
        for (int b = 0; b < 8; b++) out[(bg * 8 + b) * 18432 + o] = acc[b];
    }
}

extern "C" void kernel_launch(void* const* d_in, const int* in_sizes, int n_in,
                              void* d_out, int out_size, void* d_ws, size_t ws_size,
                              hipStream_t stream) {
    int E = in_sizes[1] / 2;

    float* ws = (float*)d_ws;
    int* flags = (int*)ws;
    float* cWg   = ws + O_WG;
    float* cAtt  = ws + O_AS;
    float* cBias = ws + O_BIAS;
    float* cBih1 = ws + O_BIH1;
    float* cBhh1 = ws + O_BHH1;
    float* cBih2 = ws + O_BIH2;
    float* cBhh2 = ws + O_BHH2;
    float* cBlin = ws + O_BLIN;

    float* base = ws + O_END;
    uint16_t* hfb = (uint16_t*)base;               // NTOT*96 bf16
    float* a_s  = base + 3145728;                  // 524288
    float* a_d  = a_s + 524288;                    // 524288
    int* deg    = (int*)(a_d + 524288);            // 65536
    int* offsL  = deg + 65536;                     // 65536
    int* bsum   = offsL + 65536;                   // 256
    int* boff   = bsum + 256;                      // 256
    int* rank   = boff + 256;                      // E
    int* ssrc   = rank + E;                        // E
    float* gT   = (float*)(ssrc + E);              // 786432
    float* Z1   = gT + 786432;                     // 49152
    float* h2l  = Z1 + 49152;                      // 4096
    size_t needed = (size_t)((h2l + 4096) - ws) * 4;
    if (ws_size < needed) return;

    k_detect<<<1, 64, 0, stream>>>((const uint16_t*)d_in[0], (const int*)d_in[1], flags);
    k_conv<<<83, 256, 0, stream>>>(d_in[2], d_in[3], d_in[4], d_in[5],
                                   d_in[8], d_in[9], d_in[12], d_in[13], d_in[15],
                                   ws, flags);
    k_zero<<<256, 256, 0, stream>>>(deg);

    k_nfa<<<2048, 256, 0, stream>>>(d_in[0], cWg, cAtt, flags, hfb, a_s, a_d);
    k_hist<<<(E + 255) / 256, 256, 0, stream>>>((const int*)d_in[1], E, flags, deg, rank);
    k_scanA<<<256, 256, 0, stream>>>(deg, offsL, bsum);
    k_scanB<<<1, 256, 0, stream>>>(bsum, boff);
    k_scatter<<<(E + 255) / 256, 256, 0, stream>>>((const int*)d_in[1], E, flags,
                                                   offsL, boff, rank, ssrc);
    k_agg<<<NTOT / 4, 256, 0, stream>>>(hfb, a_s, a_d, offsL, boff, deg, ssrc, cBias, gT);
    k_z1<<<384, 256, 0, stream>>>(gT, d_in[6], cBih1, cBhh1, flags, Z1);
    k_rec<<<32, 512, 0, stream>>>(Z1, d_in[7], d_in[10], d_in[11], cBih2, cBhh2, flags, h2l);
    k_lin<<<dim3(72, 4), 256, 0, stream>>>(h2l, d_in[14], cBlin, flags, d_out);
}

// Round 6
// 399.612 us; speedup vs baseline: 1.0815x; 1.0815x over previous
//
#include <hip/hip_runtime.h>
#include <hip/hip_bf16.h>
#include <stdint.h>

#define NTOT 65536   // B * N_NODE
#define NNODE 2048
#define CIN 12

__device__ __forceinline__ float bf2f(uint32_t u) {
    union { uint32_t i; float f; } v; v.i = u << 16; return v.f;
}
__device__ __forceinline__ uint16_t f2bf(float f) {
    union { float f; uint32_t i; } v; v.f = f;
    uint32_t x = v.i;
    uint32_t r = x + 0x7fffu + ((x >> 16) & 1u);
    return (uint16_t)(r >> 16);
}
__device__ __forceinline__ float bflo(uint32_t u) { return bf2f(u & 0xffffu); }
__device__ __forceinline__ float bfhi(uint32_t u) { return bf2f(u >> 16); }
__device__ __forceinline__ float sigmf(float x) { return 1.0f / (1.0f + __expf(-x)); }
__device__ __forceinline__ float lrelu(float v) { return v > 0.f ? v : 0.2f * v; }

// ---------------- dtype / layout detection (one wave) ----------------
__global__ void k_detect(const uint16_t* __restrict__ x16, const int* __restrict__ e32,
                         int* __restrict__ flags) {
    int lane = threadIdx.x;
    uint32_t u = x16[2 * lane];
    uint32_t ex = (u >> 7) & 0xFF;
    bool sane = (ex >= 0x60 && ex <= 0x9F) || (u == 0);
    unsigned long long bs = __ballot(sane);
    bool hi_zero = (e32[2 * lane + 1] == 0);
    unsigned long long bz = __ballot(hi_zero);
    if (lane == 0) {
        flags[0] = (__popcll(bs) >= 52) ? 1 : 0;
        flags[1] = (__popcll(bz) == 64) ? 2 : 1;
    }
}

// ---------------- small-tensor conversion to fp32 ----------------
__device__ __forceinline__ void cvt(const void* s, float* d, int i, int bf) {
    d[i] = bf ? bf2f(((const uint16_t*)s)[i]) : ((const float*)s)[i];
}

#define O_WG   16
#define O_AS   1168
#define O_AD   1264
#define O_BIAS 1360
#define O_BIH1 1376
#define O_BHH1 1504
#define O_BIH2 1632
#define O_BHH2 2144
#define O_BLIN 2656
#define O_END  21088

__global__ void __launch_bounds__(256) k_conv(
    const void* wg, const void* as_, const void* ad_, const void* bs,
    const void* b1, const void* bb1, const void* b2, const void* bb2,
    const void* bl, float* __restrict__ ws, const int* __restrict__ flags) {
    int bf = flags[0];
    int i = blockIdx.x * 256 + threadIdx.x;
    if (i < 1152)  { cvt(wg,  ws + O_WG,   i, bf); return; } i -= 1152;
    if (i < 96)    { cvt(as_, ws + O_AS,   i, bf); return; } i -= 96;
    if (i < 96)    { cvt(ad_, ws + O_AD,   i, bf); return; } i -= 96;
    if (i < 12)    { cvt(bs,  ws + O_BIAS, i, bf); return; } i -= 12;
    if (i < 128)   { cvt(b1,  ws + O_BIH1, i, bf); return; } i -= 128;
    if (i < 128)   { cvt(bb1, ws + O_BHH1, i, bf); return; } i -= 128;
    if (i < 512)   { cvt(b2,  ws + O_BIH2, i, bf); return; } i -= 512;
    if (i < 512)   { cvt(bb2, ws + O_BHH2, i, bf); return; } i -= 512;
    if (i < 18432) { cvt(bl,  ws + O_BLIN, i, bf); }
}

__global__ void k_zero(int* __restrict__ p) {
    p[blockIdx.x * 256 + threadIdx.x] = 0;
}

// ---------- fused node transform + attention scores ----------
__global__ void __launch_bounds__(256) k_nfa(const void* __restrict__ xraw,
                                             const float* __restrict__ Wg,
                                             const float* __restrict__ att,
                                             const int* __restrict__ flags,
                                             uint16_t* __restrict__ hfb,
                                             float* __restrict__ a_s, float* __restrict__ a_d) {
    __shared__ float sx[384];
    __shared__ float sw[1152];
    __shared__ float satt[192];
    __shared__ float sh[3072];
    int tid = threadIdx.x;
    int n0 = blockIdx.x * 32;
    if (flags[0]) {
        const uint32_t* xp = (const uint32_t*)xraw;
        for (int i = tid; i < 192; i += 256) {
            uint32_t u = xp[n0 * 6 + i];
            sx[2 * i] = bflo(u); sx[2 * i + 1] = bfhi(u);
        }
    } else {
        const float* xp = (const float*)xraw;
        for (int i = tid; i < 384; i += 256) sx[i] = xp[n0 * 12 + i];
    }
    for (int i = tid; i < 1152; i += 256) sw[i] = Wg[i];
    if (tid < 192) satt[tid] = att[tid];
    __syncthreads();
#pragma unroll
    for (int r = 0; r < 12; r++) {
        int idx = r * 256 + tid;
        int n = idx / 96, o = idx % 96;
        float acc = 0.f;
#pragma unroll
        for (int k = 0; k < 12; k++) acc += sx[n * 12 + k] * sw[k * 96 + o];
        sh[idx] = acc;
        hfb[n0 * 96 + idx] = f2bf(acc);
    }
    __syncthreads();
    {
        int nl = tid >> 3, h = tid & 7;
        const float* hr = sh + nl * 96 + h * 12;
        float s = 0.f, dd = 0.f;
#pragma unroll
        for (int c = 0; c < 12; c++) {
            float v = hr[c];
            s += v * satt[h * 12 + c];
            dd += v * satt[96 + h * 12 + c];
        }
        a_s[n0 * 8 + tid] = s;
        a_d[n0 * 8 + tid] = dd;
    }
}

// ---------- CSR build ----------
__global__ void k_hist(const int* __restrict__ e, int E, const int* __restrict__ flags,
                       int* __restrict__ deg, int* __restrict__ rank) {
    int i = blockIdx.x * 256 + threadIdx.x;
    if (i < E) {
        long st = flags[1];
        int d = e[st * (E + i)];
        rank[i] = atomicAdd(&deg[d], 1);
    }
}

__global__ void k_scanA(const int* __restrict__ deg, int* __restrict__ offsL,
                        int* __restrict__ bsum) {
    __shared__ int s[256];
    int t = threadIdx.x, i = blockIdx.x * 256 + t;
    int v = deg[i];
    s[t] = v; __syncthreads();
    for (int off = 1; off < 256; off <<= 1) {
        int a = (t >= off) ? s[t - off] : 0;
        __syncthreads();
        s[t] += a;
        __syncthreads();
    }
    offsL[i] = s[t] - v;
    if (t == 255) bsum[blockIdx.x] = s[255];
}

__global__ void k_scanB(const int* __restrict__ bsum, int* __restrict__ boff) {
    __shared__ int s[256];
    int t = threadIdx.x;
    int v = bsum[t];
    s[t] = v; __syncthreads();
    for (int off = 1; off < 256; off <<= 1) {
        int a = (t >= off) ? s[t - off] : 0;
        __syncthreads();
        s[t] += a;
        __syncthreads();
    }
    boff[t] = s[t] - v;
}

__global__ void k_scatter(const int* __restrict__ e, int E, const int* __restrict__ flags,
                          const int* __restrict__ offsL, const int* __restrict__ boff,
                          const int* __restrict__ rank, int* __restrict__ ssrc) {
    int i = blockIdx.x * 256 + threadIdx.x;
    if (i < E) {
        long st = flags[1];
        int s = e[st * i];
        int d = e[st * (E + i)];
        ssrc[offsL[d] + boff[d >> 8] + rank[i]] = s;
    }
}

// ---------- GAT aggregation: lane = (edge-slot, head), 8 edges/iter ----------
__global__ void __launch_bounds__(256) k_agg(
    const uint16_t* __restrict__ hfb, const float* __restrict__ a_s, const float* __restrict__ a_d,
    const int* __restrict__ offsL, const int* __restrict__ boff, const int* __restrict__ deg,
    const int* __restrict__ ssrc, const float* __restrict__ bias, float* __restrict__ gT) {
    __shared__ float sres[4][12];
    int tid = threadIdx.x, wave = tid >> 6, lane = tid & 63;
    int node = blockIdx.x * 4 + wave;
    int beg = offsL[node] + boff[node >> 8];
    int d = deg[node];
    int sub = lane >> 3, h = lane & 7;
    float adh = a_d[node * 8 + h];
    float acc[12];
    float wsum = 0.f;
#pragma unroll
    for (int c = 0; c < 12; c++) acc[c] = 0.f;
    if (sub == 0) {
        float w = __expf(lrelu(a_s[node * 8 + h] + adh));
        wsum = w;
        const uint2* hp = (const uint2*)(hfb + node * 96 + h * 12);
#pragma unroll
        for (int p = 0; p < 3; p++) {
            uint2 u = hp[p];
            acc[4 * p]     = w * bflo(u.x); acc[4 * p + 1] = w * bfhi(u.x);
            acc[4 * p + 2] = w * bflo(u.y); acc[4 * p + 3] = w * bfhi(u.y);
        }
    }
    for (int base = 0; base < d; base += 8) {
        int k = base + sub;
        if (k < d) {
            int s = ssrc[beg + k];
            float w = __expf(lrelu(a_s[s * 8 + h] + adh));
            wsum += w;
            const uint2* hp = (const uint2*)(hfb + s * 96 + h * 12);
#pragma unroll
            for (int p = 0; p < 3; p++) {
                uint2 u = hp[p];
                acc[4 * p]     += w * bflo(u.x); acc[4 * p + 1] += w * bfhi(u.x);
                acc[4 * p + 2] += w * bflo(u.y); acc[4 * p + 3] += w * bfhi(u.y);
            }
        }
    }
#pragma unroll
    for (int off = 8; off <= 32; off <<= 1) {
        wsum += __shfl_xor(wsum, off, 64);
#pragma unroll
        for (int c = 0; c < 12; c++) acc[c] += __shfl_xor(acc[c], off, 64);
    }
    float inv = 1.f / wsum;
#pragma unroll
    for (int c = 0; c < 12; c++) acc[c] *= inv;
#pragma unroll
    for (int off = 1; off <= 4; off <<= 1) {
#pragma unroll
        for (int c = 0; c < 12; c++) acc[c] += __shfl_xor(acc[c], off, 64);
    }
    if (lane == 0) {
#pragma unroll
        for (int c = 0; c < 12; c++) sres[wave][c] = acc[c];
    }
    __syncthreads();
    if (tid < 48) {
        int no = tid / 12, c = tid % 12;
        gT[c * NTOT + blockIdx.x * 4 + no] = sres[no][c] * 0.125f + bias[c];
    }
}

// ---------- Z1: 4 batches per block, weight loads shared ----------
__global__ void __launch_bounds__(256) k_z1(const float* __restrict__ gT,
                                            const void* __restrict__ Wraw,
                                            const float* __restrict__ b1,
                                            const float* __restrict__ b2,
                                            const int* __restrict__ flags,
                                            float* __restrict__ Z1) {
    int t = blockIdx.x >> 3, bg = (blockIdx.x & 7) * 4;
    __shared__ float sv[4][2048];
    __shared__ float zp[2][4][128];
    int tid = threadIdx.x;
#pragma unroll
    for (int q = 0; q < 4; q++)
        for (int v = tid; v < 2048; v += 256) sv[q][v] = gT[t * NTOT + (bg + q) * NNODE + v];
    __syncthreads();
    int row = tid & 127, half = tid >> 7;
    float a0 = 0.f, a1 = 0.f, a2 = 0.f, a3 = 0.f;
    int hbase = half * 1024;
    if (flags[0]) {
        const uint4* wp = (const uint4*)((const uint16_t*)Wraw + row * 2048 + hbase);
        for (int k = 0; k < 128; k++) {
            uint4 u = wp[k];
            float w0 = bflo(u.x), w1 = bfhi(u.x), w2 = bflo(u.y), w3 = bfhi(u.y);
            float w4 = bflo(u.z), w5 = bfhi(u.z), w6 = bflo(u.w), w7 = bfhi(u.w);
#pragma unroll
            for (int q = 0; q < 4; q++) {
                float4 A = *(const float4*)&sv[q][hbase + 8 * k];
                float4 B = *(const float4*)&sv[q][hbase + 8 * k + 4];
                float r = w0 * A.x + w1 * A.y + w2 * A.z + w3 * A.w
                        + w4 * B.x + w5 * B.y + w6 * B.z + w7 * B.w;
                if (q == 0) a0 += r; else if (q == 1) a1 += r;
                else if (q == 2) a2 += r; else a3 += r;
            }
        }
    } else {
        const float4* wp = (const float4*)((const float*)Wraw + row * 2048 + hbase);
        for (int k = 0; k < 256; k++) {
            float4 w = wp[k];
#pragma unroll
            for (int q = 0; q < 4; q++) {
                float4 A = *(const float4*)&sv[q][hbase + 4 * k];
                float r = w.x * A.x + w.y * A.y + w.z * A.z + w.w * A.w;
                if (q == 0) a0 += r; else if (q == 1) a1 += r;
                else if (q == 2) a2 += r; else a3 += r;
            }
        }
    }
    zp[half][0][row] = a0; zp[half][1][row] = a1;
    zp[half][2][row] = a2; zp[half][3][row] = a3;
    __syncthreads();
    if (tid < 128) {
        float bb = b1[tid] + b2[tid];
#pragma unroll
        for (int q = 0; q < 4; q++)
            Z1[t * 4096 + (bg + q) * 128 + tid] = zp[0][q][tid] + zp[1][q][tid] + bb;
    }
}

// ---------- LSTM1 recurrence: weights in regs, b128 LDS reads ----------
__global__ void __launch_bounds__(128) k_rec1(const float* __restrict__ Z1,
                                              const void* __restrict__ Wraw,
                                              const int* __restrict__ flags,
                                              float* __restrict__ h1a) {
    int b = blockIdx.x, row = threadIdx.x;
    __shared__ float hb[32];
    __shared__ float zb[128];
    int bf = flags[0];
    uint4 wr[4];
    if (bf) {
        const uint4* p = (const uint4*)((const uint16_t*)Wraw + row * 32);
#pragma unroll
        for (int k = 0; k < 4; k++) wr[k] = p[k];
    }
    const float4* wf = (const float4*)((const float*)Wraw + row * 32);
    if (row < 32) hb[row] = 0.f;
    float c = 0.f;
    __syncthreads();
    for (int t = 0; t < 12; t++) {
        float z = Z1[t * 4096 + b * 128 + row];
        float p0 = 0.f, p1 = 0.f;
        if (bf) {
#pragma unroll
            for (int k = 0; k < 4; k++) {
                float4 h0 = *(const float4*)&hb[8 * k];
                float4 h1 = *(const float4*)&hb[8 * k + 4];
                uint4 u = wr[k];
                p0 += bflo(u.x) * h0.x + bfhi(u.x) * h0.y + bflo(u.y) * h0.z + bfhi(u.y) * h0.w;
                p1 += bflo(u.z) * h1.x + bfhi(u.z) * h1.y + bflo(u.w) * h1.z + bfhi(u.w) * h1.w;
            }
        } else {
#pragma unroll
            for (int k = 0; k < 8; k++) {
                float4 w = wf[k];
                float4 h0 = *(const float4*)&hb[4 * k];
                p0 += w.x * h0.x + w.y * h0.y + w.z * h0.z + w.w * h0.w;
            }
        }
        zb[row] = z + p0 + p1;
        __syncthreads();
        if (row < 32) {
            float iv = zb[row], fv = zb[32 + row], gv = zb[64 + row], ov = zb[96 + row];
            c = sigmf(fv) * c + sigmf(iv) * tanhf(gv);
            float h = sigmf(ov) * tanhf(c);
            hb[row] = h;
            h1a[t * 1024 + b * 32 + row] = h;
        }
        __syncthreads();
    }
}

// ---------- Z2 input projection ----------
__global__ void k_z2(const float* __restrict__ h1a, const void* __restrict__ Wraw,
                     const float* __restrict__ b1, const float* __restrict__ b2,
                     const int* __restrict__ flags, float* __restrict__ Z2) {
    int idx = blockIdx.x * 256 + threadIdx.x;   // 12*32*512
    int t = idx >> 14;
    int r = idx & 16383;
    int b = r >> 9, row = r & 511;
    const float* hp = h1a + t * 1024 + b * 32;
    float acc = b1[row] + b2[row];
    if (flags[0]) {
        const uint2* wp = (const uint2*)((const uint16_t*)Wraw + row * 32);
#pragma unroll
        for (int k = 0; k < 8; k++) {
            uint2 u = wp[k];
            const float* h4 = hp + k * 4;
            acc += bflo(u.x) * h4[0] + bfhi(u.x) * h4[1] + bflo(u.y) * h4[2] + bfhi(u.y) * h4[3];
        }
    } else {
        const float4* wp = (const float4*)((const float*)Wraw + row * 32);
#pragma unroll
        for (int k = 0; k < 8; k++) {
            float4 w = wp[k];
            const float* h4 = hp + k * 4;
            acc += w.x * h4[0] + w.y * h4[1] + w.z * h4[2] + w.w * h4[3];
        }
    }
    Z2[idx] = acc;
}

// ---------- LSTM2 recurrence: 16-uint4 reg weights, b128 LDS reads ----------
__global__ void __launch_bounds__(512) k_rec2(const float* __restrict__ Z2,
                                              const void* __restrict__ Wraw,
                                              const int* __restrict__ flags,
                                              float* __restrict__ h2l) {
    int b = blockIdx.x, row = threadIdx.x;
    __shared__ float hb[128];
    __shared__ float zb[512];
    int bf = flags[0];
    uint4 wreg[16];
    if (bf) {
        const uint4* p = (const uint4*)((const uint16_t*)Wraw + row * 128);
#pragma unroll
        for (int k = 0; k < 16; k++) wreg[k] = p[k];
    }
    const float4* wf = (const float4*)((const float*)Wraw + row * 128);
    if (row < 128) hb[row] = 0.f;
    float c = 0.f;
    __syncthreads();
    for (int t = 0; t < 12; t++) {
        float z = Z2[t * 16384 + b * 512 + row];
        float p0 = 0.f, p1 = 0.f, p2 = 0.f, p3 = 0.f;
        if (bf) {
#pragma unroll
            for (int k = 0; k < 8; k++) {
                float4 h0 = *(const float4*)&hb[16 * k];
                float4 h1 = *(const float4*)&hb[16 * k + 4];
                float4 h2 = *(const float4*)&hb[16 * k + 8];
                float4 h3 = *(const float4*)&hb[16 * k + 12];
                uint4 ua = wreg[2 * k], ub = wreg[2 * k + 1];
                p0 += bflo(ua.x) * h0.x + bfhi(ua.x) * h0.y + bflo(ua.y) * h0.z + bfhi(ua.y) * h0.w;
                p1 += bflo(ua.z) * h1.x + bfhi(ua.z) * h1.y + bflo(ua.w) * h1.z + bfhi(ua.w) * h1.w;
                p2 += bflo(ub.x) * h2.x + bfhi(ub.x) * h2.y + bflo(ub.y) * h2.z + bfhi(ub.y) * h2.w;
                p3 += bflo(ub.z) * h3.x + bfhi(ub.z) * h3.y + bflo(ub.w) * h3.z + bfhi(ub.w) * h3.w;
            }
        } else {
#pragma unroll
            for (int k = 0; k < 8; k++) {
                float4 h0 = *(const float4*)&hb[16 * k];
                float4 h1 = *(const float4*)&hb[16 * k + 4];
                float4 h2 = *(const float4*)&hb[16 * k + 8];
                float4 h3 = *(const float4*)&hb[16 * k + 12];
                float4 w0 = wf[4 * k], w1 = wf[4 * k + 1], w2 = wf[4 * k + 2], w3 = wf[4 * k + 3];
                p0 += w0.x * h0.x + w0.y * h0.y + w0.z * h0.z + w0.w * h0.w;
                p1 += w1.x * h1.x + w1.y * h1.y + w1.z * h1.z + w1.w * h1.w;
                p2 += w2.x * h2.x + w2.y * h2.y + w2.z * h2.z + w2.w * h2.w;
                p3 += w3.x * h3.x + w3.y * h3.y + w3.z * h3.z + w3.w * h3.w;
            }
        }
        zb[row] = z + (p0 + p1) + (p2 + p3);
        __syncthreads();
        if (row < 128) {
            float iv = zb[row], fv = zb[128 + row], gv = zb[256 + row], ov = zb[384 + row];
            c = sigmf(fv) * c + sigmf(iv) * tanhf(gv);
            float h = sigmf(ov) * tanhf(c);
            hb[row] = h;
            if (t == 11) h2l[b * 128 + row] = h;
        }
        __syncthreads();
    }
}

// ---------- final linear (dual-path W) ----------
__global__ void __launch_bounds__(256) k_lin(const float* __restrict__ h2l,
                                             const void* __restrict__ Wraw,
                                             const float* __restrict__ bl,
                                             const int* __restrict__ flags,
                                             void* __restrict__ outv) {
    __shared__ float hl[8 * 128];
    int bg = blockIdx.y;
    for (int i = threadIdx.x; i < 1024; i += 256) hl[i] = h2l[bg * 1024 + i];
    __syncthreads();
    int o = blockIdx.x * 256 + threadIdx.x;
    float bb = bl[o];
    float acc[8];
#pragma unroll
    for (int b = 0; b < 8; b++) acc[b] = bb;
    int bf = flags[0];
    if (bf) {
        const uint4* wp = (const uint4*)((const uint16_t*)Wraw + o * 128);
        for (int k = 0; k < 16; k++) {
            uint4 u = wp[k];
            float w0 = bflo(u.x), w1 = bfhi(u.x), w2 = bflo(u.y), w3 = bfhi(u.y);
            float w4 = bflo(u.z), w5 = bfhi(u.z), w6 = bflo(u.w), w7 = bfhi(u.w);
#pragma unroll
            for (int b = 0; b < 8; b++) {
                const float* h8 = hl + b * 128 + k * 8;
                acc[b] += w0 * h8[0] + w1 * h8[1] + w2 * h8[2] + w3 * h8[3]
                        + w4 * h8[4] + w5 * h8[5] + w6 * h8[6] + w7 * h8[7];
            }
        }
    } else {
        const float4* wp = (const float4*)((const float*)Wraw + o * 128);
        for (int k = 0; k < 32; k++) {
            float4 w = wp[k];
#pragma unroll
            for (int b = 0; b < 8; b++) {
                const float* h4 = hl + b * 128 + k * 4;
                acc[b] += w.x * h4[0] + w.y * h4[1] + w.z * h4[2] + w.w * h4[3];
            }
        }
    }
    if (bf) {
        uint16_t* out = (uint16_t*)outv;
#pragma unroll
        for (int b = 0; b < 8; b++) out[(bg * 8 + b) * 18432 + o] = f2bf(acc[b]);
    } else {
        float* out = (float*)outv;
#pragma unroll
        for (int b = 0; b < 8; b++) out[(bg * 8 + b) * 18432 + o] = acc[b];
    }
}

extern "C" void kernel_launch(void* const* d_in, const int* in_sizes, int n_in,
                              void* d_out, int out_size, void* d_ws, size_t ws_size,
                              hipStream_t stream) {
    int E = in_sizes[1] / 2;

    float* ws = (float*)d_ws;
    int* flags = (int*)ws;
    float* cWg   = ws + O_WG;
    float* cAtt  = ws + O_AS;
    float* cBias = ws + O_BIAS;
    float* cBih1 = ws + O_BIH1;
    float* cBhh1 = ws + O_BHH1;
    float* cBih2 = ws + O_BIH2;
    float* cBhh2 = ws + O_BHH2;
    float* cBlin = ws + O_BLIN;

    float* base = ws + O_END;
    uint16_t* hfb = (uint16_t*)base;               // NTOT*96 bf16
    float* a_s  = base + 3145728;                  // 524288
    float* a_d  = a_s + 524288;                    // 524288
    int* deg    = (int*)(a_d + 524288);            // 65536
    int* offsL  = deg + 65536;                     // 65536
    int* bsum   = offsL + 65536;                   // 256
    int* boff   = bsum + 256;                      // 256
    int* rank   = boff + 256;                      // E
    int* ssrc   = rank + E;                        // E
    float* gT   = (float*)(ssrc + E);              // 786432
    float* Z1   = gT + 786432;                     // 49152
    float* h1a  = Z1 + 49152;                      // 12288
    float* Z2   = h1a + 12288;                     // 196608
    float* h2l  = Z2 + 196608;                     // 4096
    size_t needed = (size_t)((h2l + 4096) - ws) * 4;
    if (ws_size < needed) return;

    k_detect<<<1, 64, 0, stream>>>((const uint16_t*)d_in[0], (const int*)d_in[1], flags);
    k_conv<<<83, 256, 0, stream>>>(d_in[2], d_in[3], d_in[4], d_in[5],
                                   d_in[8], d_in[9], d_in[12], d_in[13], d_in[15],
                                   ws, flags);
    k_zero<<<256, 256, 0, stream>>>(deg);

    k_nfa<<<2048, 256, 0, stream>>>(d_in[0], cWg, cAtt, flags, hfb, a_s, a_d);
    k_hist<<<(E + 255) / 256, 256, 0, stream>>>((const int*)d_in[1], E, flags, deg, rank);
    k_scanA<<<256, 256, 0, stream>>>(deg, offsL, bsum);
    k_scanB<<<1, 256, 0, stream>>>(bsum, boff);
    k_scatter<<<(E + 255) / 256, 256, 0, stream>>>((const int*)d_in[1], E, flags,
                                                   offsL, boff, rank, ssrc);
    k_agg<<<NTOT / 4, 256, 0, stream>>>(hfb, a_s, a_d, offsL, boff, deg, ssrc, cBias, gT);
    k_z1<<<96, 256, 0, stream>>>(gT, d_in[6], cBih1, cBhh1, flags, Z1);
    k_rec1<<<32, 128, 0, stream>>>(Z1, d_in[7], flags, h1a);
    k_z2<<<768, 256, 0, stream>>>(h1a, d_in[10], cBih2, cBhh2, flags, Z2);
    k_rec2<<<32, 512, 0, stream>>>(Z2, d_in[11], flags, h2l);
    k_lin<<<dim3(72, 4), 256, 0, stream>>>(h2l, d_in[14], cBlin, flags, d_out);
}